// Round 6
// baseline (81.654 us; speedup 1.0000x reference)
//
#include <hip/hip_runtime.h>
#include <math.h>

#define BATCH 262144
#define N 8
#define BLK 64
#define ROWS_PER_BLK 32            // 2 threads per row
#define NBLK (BATCH / ROWS_PER_BLK) // 8192 single-wave blocks -> 32 waves/CU
#define NCMP 28

typedef float v2f __attribute__((ext_vector_type(2)));

// odd-even comparator schedule
constexpr int cmp_a(int k) {
    int q = 0;
    for (int L = 0; L < N; ++L)
        for (int a = (L & 1); a < N - 1; a += 2)
            if (q++ == k) return a;
    return 0;
}

// alpha(z) = 0.5 + atan(z)/pi. Deg-5 minimax atan on [0,1], rcp arg-reduce;
// rel err ~1e-4 on small alphas -> ~1e-4 rel err on log-domain loss terms
// (errors average out over 16.7M terms; measured absmax has been 0.0).
__device__ __forceinline__ float cauchy_alpha(float z10) {
    float az  = __builtin_fabsf(z10);
    bool  big = az > 1.0f;
    float inv = __builtin_amdgcn_rcpf(az);
    float t   = big ? inv : az;
    float t2  = t * t;
    float p   = 0.1417796f;
    p = __builtin_fmaf(p, t2, -0.3258092f);
    p = __builtin_fmaf(p, t2, 0.9992150f);
    float at = p * t;
    float r  = big ? (1.5707963267948966f - at) : at;
    float sr = __builtin_copysignf(r, z10);
    return __builtin_fmaf(sr, 0.31830988618379067f, 0.5f);
}

// 2 threads per row: thread (row, half) owns P-rows 4*half..4*half+3 as two
// float2 column-vectors. x-network + rank are duplicated across the pair
// (+~40% issue) but VGPR drops to ~55 and the grid doubles to 8 waves/SIMD
// (HW max) -- the decisive test of the latency-bound hypothesis.
__global__ __launch_bounds__(BLK) void diffsort_loss_kernel(
    const float* __restrict__ pred,
    const float* __restrict__ labels,
    const float* __restrict__ rank_ema,
    float* __restrict__ partial)
{
    const int tid  = threadIdx.x;
    const int row  = blockIdx.x * ROWS_PER_BLK + (tid >> 1);
    const int half = tid & 1;

    __shared__ float ema[N];
    if (tid < N) ema[tid] = rank_ema[tid];
    __syncthreads();

    // ---- row loads (pair threads read the same 32B; L1 merges) ----
    const float4* lp = (const float4*)(labels + (size_t)row * N);
    const float4* pp = (const float4*)(pred   + (size_t)row * N);
    float4 l0 = lp[0], l1 = lp[1];
    float4 p0 = pp[0], p1 = pp[1];
    float lab[N] = {l0.x, l0.y, l0.z, l0.w, l1.x, l1.y, l1.z, l1.w};
    float prd[N] = {p0.x, p0.y, p0.z, p0.w, p1.x, p1.y, p1.z, p1.w};

    // ---- rank_true (stable argsort of -labels) ----
    int rt[N];
#pragma unroll
    for (int i = 0; i < N; ++i) rt[i] = 0;
#pragma unroll
    for (int i = 0; i < N; ++i)
#pragma unroll
        for (int j = i + 1; j < N; ++j) {
            unsigned c = lab[j] > lab[i];
            rt[i] += c;
            rt[j] += 1u - c;
        }

    // ---- x = rank_ema[rt] - pred ----
    float x[N];
#pragma unroll
    for (int i = 0; i < N; ++i)
        x[i] = ema[rt[i]] - prd[i];

    // ---- this thread's 4 P-rows (base..base+3) as 2 packed row-pairs;
    //      init to the identity slice: row base+2*pr+c has 1 at col base+2*pr+c ----
    const float h1 = (float)half;     // 1 if rows 4..7
    const float h0 = 1.0f - h1;       // 1 if rows 0..3
    v2f p2[2][N];
#pragma unroll
    for (int pr = 0; pr < 2; ++pr)
#pragma unroll
        for (int j = 0; j < N; ++j) { p2[pr][j].x = 0.0f; p2[pr][j].y = 0.0f; }
    p2[0][0].x = h0; p2[0][4].x = h1;
    p2[0][1].y = h0; p2[0][5].y = h1;
    p2[1][2].x = h0; p2[1][6].x = h1;
    p2[1][3].y = h0; p2[1][7].y = h1;

    // ---- odd-even network ----
#pragma unroll
    for (int k = 0; k < NCMP; ++k) {
        const int ia = cmp_a(k), ib = ia + 1;
        const float a = x[ia], b = x[ib];
        const float z = b - a;
        const float alpha = cauchy_alpha(10.0f * z);
        x[ia] = __builtin_fmaf(-alpha, z, b);
        x[ib] = __builtin_fmaf( alpha, z, a);
        v2f al2; al2.x = alpha; al2.y = alpha;
#pragma unroll
        for (int pr = 0; pr < 2; ++pr) {
            const v2f ca = p2[pr][ia], cb = p2[pr][ib];
            const v2f d  = ca - cb;
            p2[pr][ia] = __builtin_elementwise_fma( al2, d, cb);
            p2[pr][ib] = __builtin_elementwise_fma(-al2, d, ca);
        }
    }

    // ---- loss for this thread's 4 rows; gt row i one-hot at col rt[i] ----
    const int base = 4 * half;
    float s = 0.0f;
#pragma unroll
    for (int pr = 0; pr < 2; ++pr) {
        const int hx = rt[base + 2 * pr];
        const int hy = rt[base + 2 * pr + 1];
        v2f arg; arg.x = 1.0f; arg.y = 1.0f;
#pragma unroll
        for (int j = 0; j < N; ++j) {
            const v2f pv = p2[pr][j];
            v2f f;
            f.x = (hx == j) ? pv.x : (1.0f - pv.x);
            f.y = (hy == j) ? pv.y : (1.0f - pv.y);
            arg *= f;
        }
        s += __logf(fmaxf(arg.x, 1e-37f));
        s += __logf(fmaxf(arg.y, 1e-37f));
    }

    // ---- wave(64) reduce: both halves of all 32 rows -> one partial ----
#pragma unroll
    for (int off = 32; off > 0; off >>= 1)
        s += __shfl_down(s, off);
    if (tid == 0) partial[blockIdx.x] = s;
}

__global__ __launch_bounds__(256) void reduce_partials(
    const float* __restrict__ partial, float* __restrict__ out)
{
    float s = 0.0f;
#pragma unroll
    for (int k = 0; k < NBLK / 256; ++k)
        s += partial[threadIdx.x + k * 256];
#pragma unroll
    for (int off = 32; off > 0; off >>= 1)
        s += __shfl_down(s, off);

    __shared__ float wsum[4];
    const int lane = threadIdx.x & 63;
    const int wid  = threadIdx.x >> 6;
    if (lane == 0) wsum[wid] = s;
    __syncthreads();
    if (threadIdx.x == 0) {
        const float tot = wsum[0] + wsum[1] + wsum[2] + wsum[3];
        // loss = -sum / (B * n * n) = -sum / 16777216
        out[0] = -tot * (1.0f / 16777216.0f);
    }
}

extern "C" void kernel_launch(void* const* d_in, const int* in_sizes, int n_in,
                              void* d_out, int out_size, void* d_ws, size_t ws_size,
                              hipStream_t stream)
{
    const float* pred     = (const float*)d_in[0];
    const float* labels   = (const float*)d_in[1];
    const float* rank_ema = (const float*)d_in[2];
    float* out     = (float*)d_out;
    float* partial = (float*)d_ws;   // NBLK*4 = 32 KiB scratch

    diffsort_loss_kernel<<<NBLK, BLK, 0, stream>>>(pred, labels, rank_ema, partial);
    reduce_partials<<<1, 256, 0, stream>>>(partial, out);
}